// Round 11
// baseline (246.103 us; speedup 1.0000x reference)
//
#include <hip/hip_runtime.h>

typedef __bf16 bf16;
typedef bf16  bf16x8 __attribute__((ext_vector_type(8)));
typedef bf16  bf16x4 __attribute__((ext_vector_type(4)));
typedef short s16x4  __attribute__((ext_vector_type(4)));
typedef float f32x4  __attribute__((ext_vector_type(4)));

#define AS1 __attribute__((address_space(1)))
#define AS3 __attribute__((address_space(3)))

#define SQLEN 2048
#define EMB   1024

// ---------------- fp32 -> bf16 convert (memory-bound) ----------------
__global__ __launch_bounds__(256) void cvt_f32_bf16(const float* __restrict__ in,
                                                    bf16* __restrict__ out, int n8) {
  int i = blockIdx.x * blockDim.x + threadIdx.x;
  if (i >= n8) return;
  const float4* p = (const float4*)in + (size_t)i * 2;
  float4 a = p[0], b = p[1];
  bf16x8 o;
  o[0] = (bf16)a.x; o[1] = (bf16)a.y; o[2] = (bf16)a.z; o[3] = (bf16)a.w;
  o[4] = (bf16)b.x; o[5] = (bf16)b.y; o[6] = (bf16)b.z; o[7] = (bf16)b.w;
  *((bf16x8*)out + i) = o;
}

// 4 weight matrices in one dispatch (blockIdx.y selects)
__global__ __launch_bounds__(256) void cvt_w4(const float* __restrict__ w0, const float* __restrict__ w1,
                                              const float* __restrict__ w2, const float* __restrict__ w3,
                                              bf16* o0, bf16* o1, bf16* o2, bf16* o3, int n8) {
  const float* in; bf16* out;
  switch (blockIdx.y) {
    case 0: in = w0; out = o0; break;
    case 1: in = w1; out = o1; break;
    case 2: in = w2; out = o2; break;
    default: in = w3; out = o3; break;
  }
  int i = blockIdx.x * blockDim.x + threadIdx.x;
  if (i >= n8) return;
  const float4* p = (const float4*)in + (size_t)i * 2;
  float4 a = p[0], b = p[1];
  bf16x8 o;
  o[0] = (bf16)a.x; o[1] = (bf16)a.y; o[2] = (bf16)a.z; o[3] = (bf16)a.w;
  o[4] = (bf16)b.x; o[5] = (bf16)b.y; o[6] = (bf16)b.z; o[7] = (bf16)b.w;
  *((bf16x8*)out + i) = o;
}

// ---------------- NT GEMM body (used by gemm_o): C[M,N] = A*B^T, f32 out ----
__device__ __forceinline__
void gemm_body_f32(const bf16* __restrict__ A, const bf16* __restrict__ B,
                   float* __restrict__ Cf, int M, int N, int K,
                   bf16* Asl, bf16* Bsl) {
  const int tid  = threadIdx.x;
  const int lane = tid & 63, wave = tid >> 6;
  const int quad = lane >> 4, col = lane & 15;
  const int m0 = blockIdx.x * 128, n0 = blockIdx.y * 128;
  const int wr = wave >> 1, wc = wave & 1;

  f32x4 acc[4][4];
  const f32x4 fz = {0.f, 0.f, 0.f, 0.f};
#pragma unroll
  for (int i = 0; i < 4; ++i)
#pragma unroll
    for (int j = 0; j < 4; ++j) acc[i][j] = fz;

  const int srow = lane >> 2;
  const int sk   = lane & 3;

  auto stage = [&](int buf, int k0) {
#pragma unroll
    for (int r = 0; r < 2; ++r) {
      const int c      = wave * 2 + r;
      const int row    = c * 16 + srow;
      const int gchunk = sk ^ (row & 3);
      const bf16* ga = A + (size_t)(m0 + row) * K + k0 + gchunk * 8;
      const bf16* gb = B + (size_t)(n0 + row) * K + k0 + gchunk * 8;
      __builtin_amdgcn_global_load_lds((const AS1 void*)ga, (AS3 void*)(Asl + buf * 4096 + c * 512), 16, 0, 0);
      __builtin_amdgcn_global_load_lds((const AS1 void*)gb, (AS3 void*)(Bsl + buf * 4096 + c * 512), 16, 0, 0);
    }
  };

  const int nk = K >> 5;
  stage(0, 0);
  for (int it = 0; it < nk; ++it) {
    __syncthreads();
    if (it + 1 < nk) stage((it + 1) & 1, (it + 1) << 5);
    const bf16* As = Asl + (it & 1) * 4096;
    const bf16* Bs = Bsl + (it & 1) * 4096;

    bf16x8 af[4], bfr[4];
#pragma unroll
    for (int i = 0; i < 4; ++i) {
      const int r = wr * 64 + i * 16 + col;
      af[i] = *(const bf16x8*)&As[r * 32 + ((quad ^ (col & 3)) * 8)];
    }
#pragma unroll
    for (int j = 0; j < 4; ++j) {
      const int r = wc * 64 + j * 16 + col;
      bfr[j] = *(const bf16x8*)&Bs[r * 32 + ((quad ^ (col & 3)) * 8)];
    }
#pragma unroll
    for (int i = 0; i < 4; ++i)
#pragma unroll
      for (int j = 0; j < 4; ++j)
        acc[i][j] = __builtin_amdgcn_mfma_f32_16x16x32_bf16(af[i], bfr[j], acc[i][j], 0, 0, 0);
  }

#pragma unroll
  for (int i = 0; i < 4; ++i) {
#pragma unroll
    for (int j = 0; j < 4; ++j) {
      const int gm0 = m0 + wr * 64 + i * 16 + quad * 4;
      const int gn  = n0 + wc * 64 + j * 16 + col;
#pragma unroll
      for (int r = 0; r < 4; ++r)
        Cf[(size_t)(gm0 + r) * N + gn] = acc[i][j][r];
    }
  }
}

// ---------------- fused QKV GEMM: one block computes Q,K,V 128x128 tiles ----
// (unchanged from R13)
__global__ __launch_bounds__(256, 2)
void gemm_qkv(const bf16* __restrict__ A, const bf16* __restrict__ Wq,
              const bf16* __restrict__ Wk, const bf16* __restrict__ Wv,
              bf16* __restrict__ Qo, bf16* __restrict__ Ko, bf16* __restrict__ Vto,
              float qscale) {
  __shared__ bf16 Asl[2 * 4096];
  __shared__ bf16 Bsl[3][2 * 4096];

  const int tid  = threadIdx.x;
  const int lane = tid & 63, wave = tid >> 6;
  const int quad = lane >> 4, col = lane & 15;
  const int m0 = blockIdx.x * 128, n0 = blockIdx.y * 128;
  const int wr = wave >> 1, wc = wave & 1;
  const int K = 1024, N = 1024;

  const bf16* const Bp[3] = {Wq, Wk, Wv};

  f32x4 acc[3][4][4];
  const f32x4 fz = {0.f, 0.f, 0.f, 0.f};
#pragma unroll
  for (int s = 0; s < 3; ++s)
#pragma unroll
    for (int i = 0; i < 4; ++i)
#pragma unroll
      for (int j = 0; j < 4; ++j) acc[s][i][j] = fz;

  const int srow = lane >> 2;
  const int sk   = lane & 3;

  auto stage = [&](int buf, int k0) {
#pragma unroll
    for (int r = 0; r < 2; ++r) {
      const int c      = wave * 2 + r;
      const int row    = c * 16 + srow;
      const int gchunk = sk ^ (row & 3);
      const bf16* ga = A + (size_t)(m0 + row) * K + k0 + gchunk * 8;
      __builtin_amdgcn_global_load_lds((const AS1 void*)ga,
          (AS3 void*)(Asl + buf * 4096 + c * 512), 16, 0, 0);
#pragma unroll
      for (int s = 0; s < 3; ++s) {
        const bf16* gb = Bp[s] + (size_t)(n0 + row) * K + k0 + gchunk * 8;
        __builtin_amdgcn_global_load_lds((const AS1 void*)gb,
            (AS3 void*)(&Bsl[s][buf * 4096 + c * 512]), 16, 0, 0);
      }
    }
  };

  const int nk = K >> 5;   // 32
  stage(0, 0);
  for (int it = 0; it < nk; ++it) {
    __syncthreads();
    if (it + 1 < nk) stage((it + 1) & 1, (it + 1) << 5);
    const bf16* As = Asl + (it & 1) * 4096;

    bf16x8 af[4];
#pragma unroll
    for (int i = 0; i < 4; ++i) {
      const int r = wr * 64 + i * 16 + col;
      af[i] = *(const bf16x8*)&As[r * 32 + ((quad ^ (col & 3)) * 8)];
    }
#pragma unroll
    for (int s = 0; s < 3; ++s) {
      const bf16* Bs = &Bsl[s][(it & 1) * 4096];
      bf16x8 bfr[4];
#pragma unroll
      for (int j = 0; j < 4; ++j) {
        const int r = wc * 64 + j * 16 + col;
        bfr[j] = *(const bf16x8*)&Bs[r * 32 + ((quad ^ (col & 3)) * 8)];
      }
#pragma unroll
      for (int i = 0; i < 4; ++i)
#pragma unroll
        for (int j = 0; j < 4; ++j)
          acc[s][i][j] = __builtin_amdgcn_mfma_f32_16x16x32_bf16(af[i], bfr[j], acc[s][i][j], 0, 0, 0);
    }
  }

  // ---- epilogue: Q (scaled), K plain, V transposed ----
#pragma unroll
  for (int s = 0; s < 3; ++s) {
    const float sc = (s == 0) ? qscale : 1.0f;
#pragma unroll
    for (int i = 0; i < 4; ++i) {
#pragma unroll
      for (int j = 0; j < 4; ++j) {
        const int gm0 = m0 + wr * 64 + i * 16 + quad * 4;
        const int gn  = n0 + wc * 64 + j * 16 + col;
        if (s == 2) {
          bf16x4 ob;
#pragma unroll
          for (int r = 0; r < 4; ++r) ob[r] = (bf16)(acc[s][i][j][r]);
          const int bb = gm0 >> 11;        // m = bb*2048 + t
          const int t_ = gm0 & 2047;
          *(bf16x4*)&Vto[((size_t)(bb * 1024 + gn)) * 2048 + t_] = ob;
        } else {
          bf16* C = (s == 0) ? Qo : Ko;
#pragma unroll
          for (int r = 0; r < 4; ++r)
            C[(size_t)(gm0 + r) * N + gn] = (bf16)(acc[s][i][j][r] * sc);
        }
      }
    }
  }
}

__global__ __launch_bounds__(256, 2)
void gemm_o(const bf16* __restrict__ A, const bf16* __restrict__ W, float* __restrict__ C) {
  __shared__ bf16 Asl[2 * 4096];
  __shared__ bf16 Bsl[2 * 4096];
  gemm_body_f32(A, W, C, 8192, 1024, 1024, Asl, Bsl);
}

// ---------------- flash causal attention, 4 waves x 2 q-strips, pipelined ----------------
// Q pre-scaled by 0.125*log2(e). Vt: [(b*1024+n), t].
// R15: DE-FENCE + STRIP PIPELINE. R13<->R14 null (LDS bytes halved, wall
// constant) proves LDS isn't binding; pipes at Mfma 34 / VALU 40 on separate
// pipes with 18% occupancy -> phase-serialized. The s_setprio pairs around
// QK and PV clusters are compile-time scheduling fences: the compiler could
// not interleave softmax VALU with MFMA clusters. Fix: (1) remove setprio;
// (2) per-iter order QK(g0) -> SM(g0) -> QK(g1) -> PV(g0) -> SM(g1) -> PV(g1)
// so dependencies allow SM(g0)||QK(g1) and SM(g1)||PV(g0) overlap in the
// scheduler. K/V fragments read per-strip (2x LDS reads vs R14 -- proven
// non-binding by the R14 null).
// Keeps: KVBLK=128 (17 paired iters), l via ones-MFMA, XCD-grouped decode,
// T13 defer-rescale, direct-to-global epilogue, R7 pairing.
__global__ __launch_bounds__(256, 2)
void attn_flash(const bf16* __restrict__ Q, const bf16* __restrict__ K,
                const bf16* __restrict__ Vt, bf16* __restrict__ Y) {
  __shared__ bf16 Ksb0[2 * 8192];   // [buf][128 keys][64 d]   32KB
  __shared__ bf16 Vsb0[2 * 8192];   // [buf][64 d][128 t]      32KB

  const int tid  = threadIdx.x;
  const int lane = tid & 63, wave = tid >> 6;   // wave 0..3
  const int quad = lane >> 4, col = lane & 15;

  // XCD-grouped decode: XCD g = bid&7 handles bh in [g*8, g*8+8)
  const int B_ = blockIdx.x;            // 0..511
  const int bh = (B_ & 7) * 8 + (B_ >> 6);
  const int p  = (B_ >> 3) & 7;         // pair index 0..7
  const int h  = bh & 15;
  const int b  = bh >> 4;
  const int hc = h * 64;
  const size_t rowBase = (size_t)b * SQLEN;

  const int srow8 = lane >> 3;
  const int sch   = lane & 7;
  const int a7    = col & 7;

  // stage one 128-key K tile + matching V^T tile; 4 waves x 4 sub-stages.
  // LDS dest wave-uniform; HW writes lane l at dest + l*16B.
  auto stageKV = [&](int buf, int t0) {
#pragma unroll
    for (int i = 0; i < 4; ++i) {
      const int krow = wave * 32 + i * 8 + srow8;          // krow&7 == srow8
      const int kch  = sch ^ srow8;
      const bf16* gk = K + (rowBase + t0 + krow) * EMB + hc + kch * 8;
      __builtin_amdgcn_global_load_lds((const AS1 void*)gk,
          (AS3 void*)(Ksb0 + buf * 8192 + wave * 2048 + i * 512), 16, 0, 0);
      const int vrow = wave * 16 + i * 4 + (lane >> 4);
      const int vch  = (lane & 15) ^ (vrow & 7);
      const bf16* gv = Vt + ((size_t)(b * EMB + hc + vrow)) * SQLEN + t0 + vch * 8;
      __builtin_amdgcn_global_load_lds((const AS1 void*)gv,
          (AS3 void*)(Vsb0 + buf * 8192 + wave * 2048 + i * 512), 16, 0, 0);
    }
  };

  const s16x4 ones = {(short)0x3F80, (short)0x3F80, (short)0x3F80, (short)0x3F80};
  const f32x4 fz = {0.f, 0.f, 0.f, 0.f};

  for (int halfIdx = 0; halfIdx < 2; ++halfIdx) {
    const int qt = halfIdx == 0 ? (15 - p) : p;  // paired: ntt sums to 17
    const int q0 = qt * 128;
    const int ntt = qt + 1;                      // 128-key tiles

    stageKV(0, 0);

    // Strip g owns q = q0 + g*64 + wave*16 + col.
    bf16x8 qf[2][2];
#pragma unroll
    for (int g = 0; g < 2; ++g) {
      const int row = g * 64 + wave * 16 + col;
      const bf16* gq = Q + (rowBase + q0 + row) * EMB + hc + quad * 8;
      qf[g][0] = *(const bf16x8*)gq;
      qf[g][1] = *(const bf16x8*)(gq + 32);
    }
    __syncthreads();   // K/V tile 0 staged

    float m_i[2] = {-INFINITY, -INFINITY};
    f32x4 o[2][4], ol[2];
#pragma unroll
    for (int g = 0; g < 2; ++g) {
#pragma unroll
      for (int dd = 0; dd < 4; ++dd) o[g][dd] = fz;
      ol[g] = fz;
    }

    for (int tt = 0; tt < ntt; ++tt) {
      const int t0 = tt * 128;
      const int cur = tt & 1;
      if (tt + 1 < ntt) stageKV(cur ^ 1, t0 + 128);  // prefetch in flight
      const bf16* Ks = Ksb0 + cur * 8192;
      const bf16* Vs = Vsb0 + cur * 8192;

      // ======== strip 0: QK^T ========
      f32x4 s0[8];
#pragma unroll
      for (int sl = 0; sl < 8; ++sl) {
        const bf16x8 kf0 = *(const bf16x8*)&Ks[(sl * 16 + col) * 64 + ((quad ^ a7) * 8)];
        const bf16x8 kf1 = *(const bf16x8*)&Ks[(sl * 16 + col) * 64 + (((quad ^ 4) ^ a7) * 8)];
        f32x4 z = fz;
        z = __builtin_amdgcn_mfma_f32_16x16x32_bf16(kf0, qf[0][0], z, 0, 0, 0);
        s0[sl] = __builtin_amdgcn_mfma_f32_16x16x32_bf16(kf1, qf[0][1], z, 0, 0, 0);
      }
      if (tt == qt) {
        const int qg = q0 + wave * 16 + col;
#pragma unroll
        for (int sl = 0; sl < 8; ++sl)
#pragma unroll
          for (int r = 0; r < 4; ++r)
            if (t0 + sl * 16 + quad * 4 + r > qg) s0[sl][r] = -INFINITY;
      }

      // ======== strip 0: softmax (overlaps strip 1 QK at sched) ========
      bf16x4 pb0[8];
      {
        float mx = s0[0][0];
#pragma unroll
        for (int sl = 0; sl < 8; ++sl)
#pragma unroll
          for (int r = 0; r < 4; ++r) mx = fmaxf(mx, s0[sl][r]);
        mx = fmaxf(mx, __shfl_xor(mx, 16));
        mx = fmaxf(mx, __shfl_xor(mx, 32));
        if (!__all(mx <= m_i[0] + 8.f)) {
          const float mnew = fmaxf(m_i[0], mx);
          const float a = __builtin_amdgcn_exp2f(m_i[0] - mnew);
#pragma unroll
          for (int dd = 0; dd < 4; ++dd) o[0][dd] *= a;
          ol[0] *= a;
          m_i[0] = mnew;
        }
#pragma unroll
        for (int sl = 0; sl < 8; ++sl)
#pragma unroll
          for (int r = 0; r < 4; ++r)
            pb0[sl][r] = (bf16)__builtin_amdgcn_exp2f(s0[sl][r] - m_i[0]);
      }

      // ======== strip 1: QK^T ========
      f32x4 s1[8];
#pragma unroll
      for (int sl = 0; sl < 8; ++sl) {
        const bf16x8 kf0 = *(const bf16x8*)&Ks[(sl * 16 + col) * 64 + ((quad ^ a7) * 8)];
        const bf16x8 kf1 = *(const bf16x8*)&Ks[(sl * 16 + col) * 64 + (((quad ^ 4) ^ a7) * 8)];
        f32x4 z = fz;
        z = __builtin_amdgcn_mfma_f32_16x16x32_bf16(kf0, qf[1][0], z, 0, 0, 0);
        s1[sl] = __builtin_amdgcn_mfma_f32_16x16x32_bf16(kf1, qf[1][1], z, 0, 0, 0);
      }
      if (tt == qt) {
        const int qg = q0 + 64 + wave * 16 + col;
#pragma unroll
        for (int sl = 0; sl < 8; ++sl)
#pragma unroll
          for (int r = 0; r < 4; ++r)
            if (t0 + sl * 16 + quad * 4 + r > qg) s1[sl][r] = -INFINITY;
      }

      // ======== strip 0: PV (overlaps strip 1 softmax at sched) ========
#pragma unroll
      for (int sl = 0; sl < 8; ++sl) {
        const s16x4 pf0 = __builtin_bit_cast(s16x4, pb0[sl]);
        ol[0] = __builtin_amdgcn_mfma_f32_16x16x16bf16_1k(ones, pf0, ol[0], 0, 0, 0);
        const int cch  = 2 * sl + (quad >> 1);
        const int half = quad & 1;
#pragma unroll
        for (int dd = 0; dd < 4; ++dd) {
          const int row = dd * 16 + col;
          const bf16x4 vb = *(const bf16x4*)&Vs[row * 128 + ((cch ^ a7) * 8) + half * 4];
          const s16x4 vf = __builtin_bit_cast(s16x4, vb);
          o[0][dd] = __builtin_amdgcn_mfma_f32_16x16x16bf16_1k(vf, pf0, o[0][dd], 0, 0, 0);
        }
      }

      // ======== strip 1: softmax ========
      bf16x4 pb1[8];
      {
        float mx = s1[0][0];
#pragma unroll
        for (int sl = 0; sl < 8; ++sl)
#pragma unroll
          for (int r = 0; r < 4; ++r) mx = fmaxf(mx, s1[sl][r]);
        mx = fmaxf(mx, __shfl_xor(mx, 16));
        mx = fmaxf(mx, __shfl_xor(mx, 32));
        if (!__all(mx <= m_i[1] + 8.f)) {
          const float mnew = fmaxf(m_i[1], mx);
          const float a = __builtin_amdgcn_exp2f(m_i[1] - mnew);
#pragma unroll
          for (int dd = 0; dd < 4; ++dd) o[1][dd] *= a;
          ol[1] *= a;
          m_i[1] = mnew;
        }
#pragma unroll
        for (int sl = 0; sl < 8; ++sl)
#pragma unroll
          for (int r = 0; r < 4; ++r)
            pb1[sl][r] = (bf16)__builtin_amdgcn_exp2f(s1[sl][r] - m_i[1]);
      }

      // ======== strip 1: PV ========
#pragma unroll
      for (int sl = 0; sl < 8; ++sl) {
        const s16x4 pf1 = __builtin_bit_cast(s16x4, pb1[sl]);
        ol[1] = __builtin_amdgcn_mfma_f32_16x16x16bf16_1k(ones, pf1, ol[1], 0, 0, 0);
        const int cch  = 2 * sl + (quad >> 1);
        const int half = quad & 1;
#pragma unroll
        for (int dd = 0; dd < 4; ++dd) {
          const int row = dd * 16 + col;
          const bf16x4 vb = *(const bf16x4*)&Vs[row * 128 + ((cch ^ a7) * 8) + half * 4];
          const s16x4 vf = __builtin_bit_cast(s16x4, vb);
          o[1][dd] = __builtin_amdgcn_mfma_f32_16x16x16bf16_1k(vf, pf1, o[1][dd], 0, 0, 0);
        }
      }

      __syncthreads();  // drains prefetch; guards dbuf reuse
    }

    // ---- epilogue: O^T/l straight to global (l replicated in every ol lane) ----
#pragma unroll
    for (int g = 0; g < 2; ++g) {
      const float rl = __builtin_amdgcn_rcpf(ol[g][0]);
      const size_t yrow = (rowBase + q0 + g * 64 + wave * 16 + col) * EMB + hc;
#pragma unroll
      for (int dd = 0; dd < 4; ++dd) {
        bf16x4 ob;
#pragma unroll
        for (int r = 0; r < 4; ++r) ob[r] = (bf16)(o[g][dd][r] * rl);
        *(bf16x4*)&Y[yrow + dd * 16 + quad * 4] = ob;
      }
    }
  }
}

// ---------------- launcher ----------------
extern "C" void kernel_launch(void* const* d_in, const int* in_sizes, int n_in,
                              void* d_out, int out_size, void* d_ws, size_t ws_size,
                              hipStream_t stream) {
  const float* x  = (const float*)d_in[0];
  const float* Wq = (const float*)d_in[1];
  const float* Wk = (const float*)d_in[2];
  const float* Wv = (const float*)d_in[3];
  const float* Wo = (const float*)d_in[4];
  float* out = (float*)d_out;

  const size_t ME = 8192ull * 1024ull;
  const size_t WE = 1024ull * 1024ull;
  bf16* ws  = (bf16*)d_ws;
  bf16* xb  = ws;
  bf16* wqb = xb + ME;
  bf16* wkb = wqb + WE;
  bf16* wvb = wkb + WE;
  bf16* wob = wvb + WE;
  bf16* Qb  = wob + WE;
  bf16* Kb  = Qb + ME;
  bf16* Vtb = Kb + ME;   // V written directly transposed by gemm_qkv
  bf16* Yb  = Vtb + ME;

  cvt_f32_bf16<<<(int)(ME / 8 / 256), 256, 0, stream>>>(x, xb, (int)(ME / 8));
  cvt_w4<<<dim3((int)(WE / 8 / 256), 4), 256, 0, stream>>>(Wq, Wk, Wv, Wo, wqb, wkb, wvb, wob, (int)(WE / 8));

  const float qscale = 0.125f * 1.4426950408889634f;
  gemm_qkv<<<dim3(64, 8), 256, 0, stream>>>(xb, wqb, wkb, wvb, Qb, Kb, Vtb, qscale);

  attn_flash<<<512, 256, 0, stream>>>(Qb, Kb, Vtb, Yb);

  gemm_o<<<dim3(64, 8), 256, 0, stream>>>(Yb, wob, out);
}

// Round 12
// 240.962 us; speedup vs baseline: 1.0213x; 1.0213x over previous
//
#include <hip/hip_runtime.h>

typedef __bf16 bf16;
typedef bf16  bf16x8 __attribute__((ext_vector_type(8)));
typedef bf16  bf16x4 __attribute__((ext_vector_type(4)));
typedef short s16x4  __attribute__((ext_vector_type(4)));
typedef float f32x4  __attribute__((ext_vector_type(4)));

#define AS1 __attribute__((address_space(1)))
#define AS3 __attribute__((address_space(3)))

#define SQLEN 2048
#define EMB   1024

// ---------------- fused fp32 -> bf16 convert: x + 4 weights, ONE dispatch ----
// R16: 5 dispatches -> 4 (probe the inter-dispatch-gap hypothesis).
// items: [0, NX) = x (8M elems /8); [NX, NX+4*NW) = Wq,Wk,Wv,Wo (1M elems /8 each).
__global__ __launch_bounds__(256) void cvt_all(const float* __restrict__ x,
                                               const float* __restrict__ w0, const float* __restrict__ w1,
                                               const float* __restrict__ w2, const float* __restrict__ w3,
                                               bf16* __restrict__ xo,
                                               bf16* o0, bf16* o1, bf16* o2, bf16* o3) {
  const int NX = 1024 * 1024;   // 8M / 8
  const int NW = 131072;        // 1M / 8
  const int i = blockIdx.x * blockDim.x + threadIdx.x;  // grid = 6144*256 exactly
  const float* in; bf16* out; int idx;
  if (i < NX) { in = x; out = xo; idx = i; }
  else {
    const int j = i - NX;
    const int w = j >> 17;      // NW = 2^17
    idx = j & (NW - 1);
    switch (w) {
      case 0: in = w0; out = o0; break;
      case 1: in = w1; out = o1; break;
      case 2: in = w2; out = o2; break;
      default: in = w3; out = o3; break;
    }
  }
  const float4* p = (const float4*)in + (size_t)idx * 2;
  float4 a = p[0], b = p[1];
  bf16x8 o;
  o[0] = (bf16)a.x; o[1] = (bf16)a.y; o[2] = (bf16)a.z; o[3] = (bf16)a.w;
  o[4] = (bf16)b.x; o[5] = (bf16)b.y; o[6] = (bf16)b.z; o[7] = (bf16)b.w;
  *((bf16x8*)out + idx) = o;
}

// ---------------- fused QKV GEMM: one block computes Q,K,V 128x128 tiles ----
// (unchanged from R13)
__global__ __launch_bounds__(256, 2)
void gemm_qkv(const bf16* __restrict__ A, const bf16* __restrict__ Wq,
              const bf16* __restrict__ Wk, const bf16* __restrict__ Wv,
              bf16* __restrict__ Qo, bf16* __restrict__ Ko, bf16* __restrict__ Vto,
              float qscale) {
  __shared__ bf16 Asl[2 * 4096];
  __shared__ bf16 Bsl[3][2 * 4096];

  const int tid  = threadIdx.x;
  const int lane = tid & 63, wave = tid >> 6;
  const int quad = lane >> 4, col = lane & 15;
  const int m0 = blockIdx.x * 128, n0 = blockIdx.y * 128;
  const int wr = wave >> 1, wc = wave & 1;
  const int K = 1024, N = 1024;

  const bf16* const Bp[3] = {Wq, Wk, Wv};

  f32x4 acc[3][4][4];
  const f32x4 fz = {0.f, 0.f, 0.f, 0.f};
#pragma unroll
  for (int s = 0; s < 3; ++s)
#pragma unroll
    for (int i = 0; i < 4; ++i)
#pragma unroll
      for (int j = 0; j < 4; ++j) acc[s][i][j] = fz;

  const int srow = lane >> 2;
  const int sk   = lane & 3;

  auto stage = [&](int buf, int k0) {
#pragma unroll
    for (int r = 0; r < 2; ++r) {
      const int c      = wave * 2 + r;
      const int row    = c * 16 + srow;
      const int gchunk = sk ^ (row & 3);
      const bf16* ga = A + (size_t)(m0 + row) * K + k0 + gchunk * 8;
      __builtin_amdgcn_global_load_lds((const AS1 void*)ga,
          (AS3 void*)(Asl + buf * 4096 + c * 512), 16, 0, 0);
#pragma unroll
      for (int s = 0; s < 3; ++s) {
        const bf16* gb = Bp[s] + (size_t)(n0 + row) * K + k0 + gchunk * 8;
        __builtin_amdgcn_global_load_lds((const AS1 void*)gb,
            (AS3 void*)(&Bsl[s][buf * 4096 + c * 512]), 16, 0, 0);
      }
    }
  };

  const int nk = K >> 5;   // 32
  stage(0, 0);
  for (int it = 0; it < nk; ++it) {
    __syncthreads();
    if (it + 1 < nk) stage((it + 1) & 1, (it + 1) << 5);
    const bf16* As = Asl + (it & 1) * 4096;

    bf16x8 af[4];
#pragma unroll
    for (int i = 0; i < 4; ++i) {
      const int r = wr * 64 + i * 16 + col;
      af[i] = *(const bf16x8*)&As[r * 32 + ((quad ^ (col & 3)) * 8)];
    }
#pragma unroll
    for (int s = 0; s < 3; ++s) {
      const bf16* Bs = &Bsl[s][(it & 1) * 4096];
      bf16x8 bfr[4];
#pragma unroll
      for (int j = 0; j < 4; ++j) {
        const int r = wc * 64 + j * 16 + col;
        bfr[j] = *(const bf16x8*)&Bs[r * 32 + ((quad ^ (col & 3)) * 8)];
      }
#pragma unroll
      for (int i = 0; i < 4; ++i)
#pragma unroll
        for (int j = 0; j < 4; ++j)
          acc[s][i][j] = __builtin_amdgcn_mfma_f32_16x16x32_bf16(af[i], bfr[j], acc[s][i][j], 0, 0, 0);
    }
  }

  // ---- epilogue: Q (scaled), K plain, V transposed ----
#pragma unroll
  for (int s = 0; s < 3; ++s) {
    const float sc = (s == 0) ? qscale : 1.0f;
#pragma unroll
    for (int i = 0; i < 4; ++i) {
#pragma unroll
      for (int j = 0; j < 4; ++j) {
        const int gm0 = m0 + wr * 64 + i * 16 + quad * 4;
        const int gn  = n0 + wc * 64 + j * 16 + col;
        if (s == 2) {
          bf16x4 ob;
#pragma unroll
          for (int r = 0; r < 4; ++r) ob[r] = (bf16)(acc[s][i][j][r]);
          const int bb = gm0 >> 11;        // m = bb*2048 + t
          const int t_ = gm0 & 2047;
          *(bf16x4*)&Vto[((size_t)(bb * 1024 + gn)) * 2048 + t_] = ob;
        } else {
          bf16* C = (s == 0) ? Qo : Ko;
#pragma unroll
          for (int r = 0; r < 4; ++r)
            C[(size_t)(gm0 + r) * N + gn] = (bf16)(acc[s][i][j][r] * sc);
        }
      }
    }
  }
}

// ---------------- output GEMM: C[8192,1024] = Y * Wo^T, f32 out ----
// R16: 2 K-chunks per barrier (R13's MFMA-per-overhead mechanism applied to
// gemm_o). 4-slot LDS ring = pair-granular double buffer (64KB, 2 blocks/CU,
// grid 512 = 2/CU). Per barrier-iter: prefetch next chunk PAIR, compute
// current pair = 32 MFMA/wave/barrier (was 16). Slot safety: prefetch at
// iter p targets slots whose readers finished before iter p's barrier.
__global__ __launch_bounds__(256, 2)
void gemm_o(const bf16* __restrict__ A, const bf16* __restrict__ W, float* __restrict__ Cf) {
  __shared__ bf16 Asl[4 * 4096];   // 32KB: slots 0..3 (chunk & 3)
  __shared__ bf16 Bsl[4 * 4096];   // 32KB

  const int tid  = threadIdx.x;
  const int lane = tid & 63, wave = tid >> 6;
  const int quad = lane >> 4, col = lane & 15;
  const int m0 = blockIdx.x * 128, n0 = blockIdx.y * 128;
  const int wr = wave >> 1, wc = wave & 1;
  const int K = 1024, N = 1024;

  f32x4 acc[4][4];
  const f32x4 fz = {0.f, 0.f, 0.f, 0.f};
#pragma unroll
  for (int i = 0; i < 4; ++i)
#pragma unroll
    for (int j = 0; j < 4; ++j) acc[i][j] = fz;

  const int srow = lane >> 2;
  const int sk   = lane & 3;

  auto stage = [&](int slot, int k0) {
#pragma unroll
    for (int r = 0; r < 2; ++r) {
      const int c      = wave * 2 + r;
      const int row    = c * 16 + srow;
      const int gchunk = sk ^ (row & 3);
      const bf16* ga = A + (size_t)(m0 + row) * K + k0 + gchunk * 8;
      const bf16* gb = W + (size_t)(n0 + row) * K + k0 + gchunk * 8;
      __builtin_amdgcn_global_load_lds((const AS1 void*)ga, (AS3 void*)(Asl + slot * 4096 + c * 512), 16, 0, 0);
      __builtin_amdgcn_global_load_lds((const AS1 void*)gb, (AS3 void*)(Bsl + slot * 4096 + c * 512), 16, 0, 0);
    }
  };

  stage(0, 0);
  stage(1, 32);
  for (int pp = 0; pp < 16; ++pp) {          // 16 barrier-iters, 2 chunks each
    __syncthreads();
    if (pp + 1 < 16) {
      stage((2 * pp + 2) & 3, (2 * pp + 2) * 32);
      stage((2 * pp + 3) & 3, (2 * pp + 3) * 32);
    }
#pragma unroll
    for (int h = 0; h < 2; ++h) {
      const int ck = 2 * pp + h;
      const bf16* As = Asl + (ck & 3) * 4096;
      const bf16* Bs = Bsl + (ck & 3) * 4096;

      bf16x8 af[4], bfr[4];
#pragma unroll
      for (int i = 0; i < 4; ++i) {
        const int r = wr * 64 + i * 16 + col;
        af[i] = *(const bf16x8*)&As[r * 32 + ((quad ^ (col & 3)) * 8)];
      }
#pragma unroll
      for (int j = 0; j < 4; ++j) {
        const int r = wc * 64 + j * 16 + col;
        bfr[j] = *(const bf16x8*)&Bs[r * 32 + ((quad ^ (col & 3)) * 8)];
      }
#pragma unroll
      for (int i = 0; i < 4; ++i)
#pragma unroll
        for (int j = 0; j < 4; ++j)
          acc[i][j] = __builtin_amdgcn_mfma_f32_16x16x32_bf16(af[i], bfr[j], acc[i][j], 0, 0, 0);
    }
  }

#pragma unroll
  for (int i = 0; i < 4; ++i) {
#pragma unroll
    for (int j = 0; j < 4; ++j) {
      const int gm0 = m0 + wr * 64 + i * 16 + quad * 4;
      const int gn  = n0 + wc * 64 + j * 16 + col;
#pragma unroll
      for (int r = 0; r < 4; ++r)
        Cf[(size_t)(gm0 + r) * N + gn] = acc[i][j][r];
    }
  }
}

// ---------------- flash causal attention, 4 waves x 2 q-strips, pipelined ----------------
// (unchanged from R15 — attn stuck at ~73us across 3 structural variants;
// parked pending a T4 counted-vmcnt restructure)
__global__ __launch_bounds__(256, 2)
void attn_flash(const bf16* __restrict__ Q, const bf16* __restrict__ K,
                const bf16* __restrict__ Vt, bf16* __restrict__ Y) {
  __shared__ bf16 Ksb0[2 * 8192];   // [buf][128 keys][64 d]   32KB
  __shared__ bf16 Vsb0[2 * 8192];   // [buf][64 d][128 t]      32KB

  const int tid  = threadIdx.x;
  const int lane = tid & 63, wave = tid >> 6;   // wave 0..3
  const int quad = lane >> 4, col = lane & 15;

  // XCD-grouped decode: XCD g = bid&7 handles bh in [g*8, g*8+8)
  const int B_ = blockIdx.x;            // 0..511
  const int bh = (B_ & 7) * 8 + (B_ >> 6);
  const int p  = (B_ >> 3) & 7;         // pair index 0..7
  const int h  = bh & 15;
  const int b  = bh >> 4;
  const int hc = h * 64;
  const size_t rowBase = (size_t)b * SQLEN;

  const int srow8 = lane >> 3;
  const int sch   = lane & 7;
  const int a7    = col & 7;

  auto stageKV = [&](int buf, int t0) {
#pragma unroll
    for (int i = 0; i < 4; ++i) {
      const int krow = wave * 32 + i * 8 + srow8;          // krow&7 == srow8
      const int kch  = sch ^ srow8;
      const bf16* gk = K + (rowBase + t0 + krow) * EMB + hc + kch * 8;
      __builtin_amdgcn_global_load_lds((const AS1 void*)gk,
          (AS3 void*)(Ksb0 + buf * 8192 + wave * 2048 + i * 512), 16, 0, 0);
      const int vrow = wave * 16 + i * 4 + (lane >> 4);
      const int vch  = (lane & 15) ^ (vrow & 7);
      const bf16* gv = Vt + ((size_t)(b * EMB + hc + vrow)) * SQLEN + t0 + vch * 8;
      __builtin_amdgcn_global_load_lds((const AS1 void*)gv,
          (AS3 void*)(Vsb0 + buf * 8192 + wave * 2048 + i * 512), 16, 0, 0);
    }
  };

  const s16x4 ones = {(short)0x3F80, (short)0x3F80, (short)0x3F80, (short)0x3F80};
  const f32x4 fz = {0.f, 0.f, 0.f, 0.f};

  for (int halfIdx = 0; halfIdx < 2; ++halfIdx) {
    const int qt = halfIdx == 0 ? (15 - p) : p;  // paired: ntt sums to 17
    const int q0 = qt * 128;
    const int ntt = qt + 1;                      // 128-key tiles

    stageKV(0, 0);

    // Strip g owns q = q0 + g*64 + wave*16 + col.
    bf16x8 qf[2][2];
#pragma unroll
    for (int g = 0; g < 2; ++g) {
      const int row = g * 64 + wave * 16 + col;
      const bf16* gq = Q + (rowBase + q0 + row) * EMB + hc + quad * 8;
      qf[g][0] = *(const bf16x8*)gq;
      qf[g][1] = *(const bf16x8*)(gq + 32);
    }
    __syncthreads();   // K/V tile 0 staged

    float m_i[2] = {-INFINITY, -INFINITY};
    f32x4 o[2][4], ol[2];
#pragma unroll
    for (int g = 0; g < 2; ++g) {
#pragma unroll
      for (int dd = 0; dd < 4; ++dd) o[g][dd] = fz;
      ol[g] = fz;
    }

    for (int tt = 0; tt < ntt; ++tt) {
      const int t0 = tt * 128;
      const int cur = tt & 1;
      if (tt + 1 < ntt) stageKV(cur ^ 1, t0 + 128);  // prefetch in flight
      const bf16* Ks = Ksb0 + cur * 8192;
      const bf16* Vs = Vsb0 + cur * 8192;

      // ======== strip 0: QK^T ========
      f32x4 s0[8];
#pragma unroll
      for (int sl = 0; sl < 8; ++sl) {
        const bf16x8 kf0 = *(const bf16x8*)&Ks[(sl * 16 + col) * 64 + ((quad ^ a7) * 8)];
        const bf16x8 kf1 = *(const bf16x8*)&Ks[(sl * 16 + col) * 64 + (((quad ^ 4) ^ a7) * 8)];
        f32x4 z = fz;
        z = __builtin_amdgcn_mfma_f32_16x16x32_bf16(kf0, qf[0][0], z, 0, 0, 0);
        s0[sl] = __builtin_amdgcn_mfma_f32_16x16x32_bf16(kf1, qf[0][1], z, 0, 0, 0);
      }
      if (tt == qt) {
        const int qg = q0 + wave * 16 + col;
#pragma unroll
        for (int sl = 0; sl < 8; ++sl)
#pragma unroll
          for (int r = 0; r < 4; ++r)
            if (t0 + sl * 16 + quad * 4 + r > qg) s0[sl][r] = -INFINITY;
      }

      // ======== strip 0: softmax (overlaps strip 1 QK at sched) ========
      bf16x4 pb0[8];
      {
        float mx = s0[0][0];
#pragma unroll
        for (int sl = 0; sl < 8; ++sl)
#pragma unroll
          for (int r = 0; r < 4; ++r) mx = fmaxf(mx, s0[sl][r]);
        mx = fmaxf(mx, __shfl_xor(mx, 16));
        mx = fmaxf(mx, __shfl_xor(mx, 32));
        if (!__all(mx <= m_i[0] + 8.f)) {
          const float mnew = fmaxf(m_i[0], mx);
          const float a = __builtin_amdgcn_exp2f(m_i[0] - mnew);
#pragma unroll
          for (int dd = 0; dd < 4; ++dd) o[0][dd] *= a;
          ol[0] *= a;
          m_i[0] = mnew;
        }
#pragma unroll
        for (int sl = 0; sl < 8; ++sl)
#pragma unroll
          for (int r = 0; r < 4; ++r)
            pb0[sl][r] = (bf16)__builtin_amdgcn_exp2f(s0[sl][r] - m_i[0]);
      }

      // ======== strip 1: QK^T ========
      f32x4 s1[8];
#pragma unroll
      for (int sl = 0; sl < 8; ++sl) {
        const bf16x8 kf0 = *(const bf16x8*)&Ks[(sl * 16 + col) * 64 + ((quad ^ a7) * 8)];
        const bf16x8 kf1 = *(const bf16x8*)&Ks[(sl * 16 + col) * 64 + (((quad ^ 4) ^ a7) * 8)];
        f32x4 z = fz;
        z = __builtin_amdgcn_mfma_f32_16x16x32_bf16(kf0, qf[1][0], z, 0, 0, 0);
        s1[sl] = __builtin_amdgcn_mfma_f32_16x16x32_bf16(kf1, qf[1][1], z, 0, 0, 0);
      }
      if (tt == qt) {
        const int qg = q0 + 64 + wave * 16 + col;
#pragma unroll
        for (int sl = 0; sl < 8; ++sl)
#pragma unroll
          for (int r = 0; r < 4; ++r)
            if (t0 + sl * 16 + quad * 4 + r > qg) s1[sl][r] = -INFINITY;
      }

      // ======== strip 0: PV (overlaps strip 1 softmax at sched) ========
#pragma unroll
      for (int sl = 0; sl < 8; ++sl) {
        const s16x4 pf0 = __builtin_bit_cast(s16x4, pb0[sl]);
        ol[0] = __builtin_amdgcn_mfma_f32_16x16x16bf16_1k(ones, pf0, ol[0], 0, 0, 0);
        const int cch  = 2 * sl + (quad >> 1);
        const int half = quad & 1;
#pragma unroll
        for (int dd = 0; dd < 4; ++dd) {
          const int row = dd * 16 + col;
          const bf16x4 vb = *(const bf16x4*)&Vs[row * 128 + ((cch ^ a7) * 8) + half * 4];
          const s16x4 vf = __builtin_bit_cast(s16x4, vb);
          o[0][dd] = __builtin_amdgcn_mfma_f32_16x16x16bf16_1k(vf, pf0, o[0][dd], 0, 0, 0);
        }
      }

      // ======== strip 1: softmax ========
      bf16x4 pb1[8];
      {
        float mx = s1[0][0];
#pragma unroll
        for (int sl = 0; sl < 8; ++sl)
#pragma unroll
          for (int r = 0; r < 4; ++r) mx = fmaxf(mx, s1[sl][r]);
        mx = fmaxf(mx, __shfl_xor(mx, 16));
        mx = fmaxf(mx, __shfl_xor(mx, 32));
        if (!__all(mx <= m_i[1] + 8.f)) {
          const float mnew = fmaxf(m_i[1], mx);
          const float a = __builtin_amdgcn_exp2f(m_i[1] - mnew);
#pragma unroll
          for (int dd = 0; dd < 4; ++dd) o[1][dd] *= a;
          ol[1] *= a;
          m_i[1] = mnew;
        }
#pragma unroll
        for (int sl = 0; sl < 8; ++sl)
#pragma unroll
          for (int r = 0; r < 4; ++r)
            pb1[sl][r] = (bf16)__builtin_amdgcn_exp2f(s1[sl][r] - m_i[1]);
      }

      // ======== strip 1: PV ========
#pragma unroll
      for (int sl = 0; sl < 8; ++sl) {
        const s16x4 pf1 = __builtin_bit_cast(s16x4, pb1[sl]);
        ol[1] = __builtin_amdgcn_mfma_f32_16x16x16bf16_1k(ones, pf1, ol[1], 0, 0, 0);
        const int cch  = 2 * sl + (quad >> 1);
        const int half = quad & 1;
#pragma unroll
        for (int dd = 0; dd < 4; ++dd) {
          const int row = dd * 16 + col;
          const bf16x4 vb = *(const bf16x4*)&Vs[row * 128 + ((cch ^ a7) * 8) + half * 4];
          const s16x4 vf = __builtin_bit_cast(s16x4, vb);
          o[1][dd] = __builtin_amdgcn_mfma_f32_16x16x16bf16_1k(vf, pf1, o[1][dd], 0, 0, 0);
        }
      }

      __syncthreads();  // drains prefetch; guards dbuf reuse
    }

    // ---- epilogue: O^T/l straight to global (l replicated in every ol lane) ----
#pragma unroll
    for (int g = 0; g < 2; ++g) {
      const float rl = __builtin_amdgcn_rcpf(ol[g][0]);
      const size_t yrow = (rowBase + q0 + g * 64 + wave * 16 + col) * EMB + hc;
#pragma unroll
      for (int dd = 0; dd < 4; ++dd) {
        bf16x4 ob;
#pragma unroll
        for (int r = 0; r < 4; ++r) ob[r] = (bf16)(o[g][dd][r] * rl);
        *(bf16x4*)&Y[yrow + dd * 16 + quad * 4] = ob;
      }
    }
  }
}

// ---------------- launcher ----------------
extern "C" void kernel_launch(void* const* d_in, const int* in_sizes, int n_in,
                              void* d_out, int out_size, void* d_ws, size_t ws_size,
                              hipStream_t stream) {
  const float* x  = (const float*)d_in[0];
  const float* Wq = (const float*)d_in[1];
  const float* Wk = (const float*)d_in[2];
  const float* Wv = (const float*)d_in[3];
  const float* Wo = (const float*)d_in[4];
  float* out = (float*)d_out;

  const size_t ME = 8192ull * 1024ull;
  const size_t WE = 1024ull * 1024ull;
  bf16* ws  = (bf16*)d_ws;
  bf16* xb  = ws;
  bf16* wqb = xb + ME;
  bf16* wkb = wqb + WE;
  bf16* wvb = wkb + WE;
  bf16* wob = wvb + WE;
  bf16* Qb  = wob + WE;
  bf16* Kb  = Qb + ME;
  bf16* Vtb = Kb + ME;   // V written directly transposed by gemm_qkv
  bf16* Yb  = Vtb + ME;

  // one convert dispatch: 6144 blocks cover x (4096) + 4 weights (2048)
  cvt_all<<<6144, 256, 0, stream>>>(x, Wq, Wk, Wv, Wo, xb, wqb, wkb, wvb, wob);

  const float qscale = 0.125f * 1.4426950408889634f;
  gemm_qkv<<<dim3(64, 8), 256, 0, stream>>>(xb, wqb, wkb, wvb, Qb, Kb, Vtb, qscale);

  attn_flash<<<512, 256, 0, stream>>>(Qb, Kb, Vtb, Yb);

  gemm_o<<<dim3(64, 8), 256, 0, stream>>>(Yb, wob, out);
}